// Round 2
// baseline (1507.229 us; speedup 1.0000x reference)
//
#include <hip/hip_runtime.h>
#include <math.h>

#define D 256
#define DOUT 40

// ---------------- degree histogram ----------------
__global__ __launch_bounds__(256) void k_degree(const int* __restrict__ src,
                                                const int* __restrict__ dst,
                                                int* __restrict__ outdeg,
                                                int* __restrict__ indeg, int E) {
    int e = blockIdx.x * 256 + threadIdx.x;
    if (e < E) {
        atomicAdd(&outdeg[src[e]], 1);
        atomicAdd(&indeg[dst[e]], 1);
    }
}

// ---------------- inv-sqrt norm factors ----------------
__global__ __launch_bounds__(256) void k_invsqrt(const int* __restrict__ outdeg,
                                                 const int* __restrict__ indeg,
                                                 float* __restrict__ inv_out,
                                                 float* __restrict__ inv_in, int n) {
    int i = blockIdx.x * 256 + threadIdx.x;
    if (i < n) {
        int od = outdeg[i], idg = indeg[i];
        inv_out[i] = od > 0 ? rsqrtf((float)od) : 0.0f;
        inv_in[i]  = idg > 0 ? rsqrtf((float)idg) : 0.0f;
    }
}

// ---------------- one-block exclusive scan (offsets) ----------------
__global__ __launch_bounds__(1024) void k_scan(const int* __restrict__ deg,
                                               int* __restrict__ offs, int n) {
    __shared__ int wsum[16];
    __shared__ int s_carry;
    int tid = threadIdx.x;
    int lane = tid & 63, wv = tid >> 6;
    if (tid == 0) s_carry = 0;
    __syncthreads();
    for (int base = 0; base < n; base += 1024) {
        int i = base + tid;
        int v = (i < n) ? deg[i] : 0;
        int x = v;
        #pragma unroll
        for (int o = 1; o < 64; o <<= 1) {
            int t = __shfl_up(x, o);
            if (lane >= o) x += t;
        }
        if (lane == 63) wsum[wv] = x;
        __syncthreads();
        if (wv == 0 && lane < 16) {
            int y = wsum[lane];
            #pragma unroll
            for (int o = 1; o < 16; o <<= 1) {
                int t = __shfl_up(y, o);
                if (lane >= o) y += t;
            }
            wsum[lane] = y;
        }
        __syncthreads();
        int waveoff = (wv == 0) ? 0 : wsum[wv - 1];
        if (i < n) offs[i] = s_carry + waveoff + x - v;
        __syncthreads();
        if (tid == 0) s_carry += wsum[15];
        __syncthreads();
    }
    if (threadIdx.x == 0) offs[n] = s_carry;
}

// ---------------- CSR scatter (group edges by dst) ----------------
__global__ __launch_bounds__(256) void k_scatter(const int* __restrict__ src,
                                                 const int* __restrict__ dst,
                                                 const int* __restrict__ offs,
                                                 int* __restrict__ cursor,
                                                 const float* __restrict__ inv_out,
                                                 int* __restrict__ csr_src,
                                                 float* __restrict__ csr_w, int E) {
    int e = blockIdx.x * 256 + threadIdx.x;
    if (e < E) {
        int d = dst[e], s = src[e];
        int p = atomicAdd(&cursor[d], 1);
        int idx = offs[d] + p;
        csr_src[idx] = s;
        csr_w[idx] = inv_out[s];
    }
}

// ---------------- SpMM, D=256: one wave per dst node ----------------
__global__ __launch_bounds__(256) void k_spmm256(const float* __restrict__ h,
                                                 const int* __restrict__ offs,
                                                 const int* __restrict__ csr_src,
                                                 const float* __restrict__ csr_w,
                                                 const float* __restrict__ inv_in,
                                                 float* __restrict__ out, int n) {
    int wid = (blockIdx.x * 256 + threadIdx.x) >> 6;
    int lane = threadIdx.x & 63;
    if (wid >= n) return;
    int beg = offs[wid], end = offs[wid + 1];
    float4 acc = make_float4(0.f, 0.f, 0.f, 0.f);
    int j = beg;
    for (; j + 4 <= end; j += 4) {
        int s0 = csr_src[j], s1 = csr_src[j + 1], s2 = csr_src[j + 2], s3 = csr_src[j + 3];
        float w0 = csr_w[j], w1 = csr_w[j + 1], w2 = csr_w[j + 2], w3 = csr_w[j + 3];
        float4 v0 = *(reinterpret_cast<const float4*>(h + (size_t)s0 * D) + lane);
        float4 v1 = *(reinterpret_cast<const float4*>(h + (size_t)s1 * D) + lane);
        float4 v2 = *(reinterpret_cast<const float4*>(h + (size_t)s2 * D) + lane);
        float4 v3 = *(reinterpret_cast<const float4*>(h + (size_t)s3 * D) + lane);
        acc.x += w0 * v0.x; acc.y += w0 * v0.y; acc.z += w0 * v0.z; acc.w += w0 * v0.w;
        acc.x += w1 * v1.x; acc.y += w1 * v1.y; acc.z += w1 * v1.z; acc.w += w1 * v1.w;
        acc.x += w2 * v2.x; acc.y += w2 * v2.y; acc.z += w2 * v2.z; acc.w += w2 * v2.w;
        acc.x += w3 * v3.x; acc.y += w3 * v3.y; acc.z += w3 * v3.z; acc.w += w3 * v3.w;
    }
    for (; j < end; ++j) {
        int s = csr_src[j];
        float w = csr_w[j];
        float4 v = *(reinterpret_cast<const float4*>(h + (size_t)s * D) + lane);
        acc.x += w * v.x; acc.y += w * v.y; acc.z += w * v.z; acc.w += w * v.w;
    }
    float sc = inv_in[wid];
    float4 r = make_float4(sc * acc.x, sc * acc.y, sc * acc.z, sc * acc.w);
    *(reinterpret_cast<float4*>(out + (size_t)wid * D) + lane) = r;
}

// ---------------- f32 GEMM: C[M,256] = act(A[M,256] @ W[256,256] + b) ----------------
#define BM 128
#define BN 128
#define BK 32
__global__ __launch_bounds__(256) void k_gemm_fused(const float* __restrict__ A,
                                                    const float* __restrict__ W,
                                                    const float* __restrict__ bias,
                                                    float* __restrict__ C, int M,
                                                    int do_relu) {
    __shared__ float As[BK][BM + 4];   // [k][row], pad keeps 16B alignment
    __shared__ float Ws[BK][BN];       // [k][col]
    int tid = threadIdx.x;
    int rowBase = blockIdx.x * BM;
    int cb = blockIdx.y;
    int f4 = tid & 7, rr = tid >> 3;      // A staging
    int c4 = tid & 31, kk = tid >> 5;     // W staging
    int ty = tid >> 4, tx = tid & 15;     // compute 8x8 micro-tile

    float acc[8][8];
    #pragma unroll
    for (int i = 0; i < 8; ++i)
        #pragma unroll
        for (int j = 0; j < 8; ++j) acc[i][j] = 0.f;

    for (int k0 = 0; k0 < 256; k0 += BK) {
        #pragma unroll
        for (int i = 0; i < 4; ++i) {
            int row = rowBase + rr + i * 32;
            float4 v = make_float4(0.f, 0.f, 0.f, 0.f);
            if (row < M)
                v = *reinterpret_cast<const float4*>(A + (size_t)row * 256 + k0 + f4 * 4);
            As[f4 * 4 + 0][rr + i * 32] = v.x;
            As[f4 * 4 + 1][rr + i * 32] = v.y;
            As[f4 * 4 + 2][rr + i * 32] = v.z;
            As[f4 * 4 + 3][rr + i * 32] = v.w;
        }
        #pragma unroll
        for (int i = 0; i < 4; ++i) {
            int k = kk * 4 + i;
            *reinterpret_cast<float4*>(&Ws[k][c4 * 4]) =
                *reinterpret_cast<const float4*>(W + (size_t)(k0 + k) * 256 + cb * BN + c4 * 4);
        }
        __syncthreads();
        #pragma unroll
        for (int k = 0; k < BK; ++k) {
            float4 a0 = *reinterpret_cast<const float4*>(&As[k][ty * 8]);
            float4 a1 = *reinterpret_cast<const float4*>(&As[k][ty * 8 + 4]);
            float4 w0 = *reinterpret_cast<const float4*>(&Ws[k][tx * 8]);
            float4 w1 = *reinterpret_cast<const float4*>(&Ws[k][tx * 8 + 4]);
            float av[8] = {a0.x, a0.y, a0.z, a0.w, a1.x, a1.y, a1.z, a1.w};
            float wv[8] = {w0.x, w0.y, w0.z, w0.w, w1.x, w1.y, w1.z, w1.w};
            #pragma unroll
            for (int i = 0; i < 8; ++i)
                #pragma unroll
                for (int j = 0; j < 8; ++j) acc[i][j] += av[i] * wv[j];
        }
        __syncthreads();
    }

    float bv[8];
    #pragma unroll
    for (int j = 0; j < 8; ++j) bv[j] = bias[cb * BN + tx * 8 + j];
    #pragma unroll
    for (int i = 0; i < 8; ++i) {
        int row = rowBase + ty * 8 + i;
        if (row < M) {
            float o[8];
            #pragma unroll
            for (int j = 0; j < 8; ++j) {
                float v = acc[i][j] + bv[j];
                o[j] = do_relu ? fmaxf(v, 0.f) : v;
            }
            float4* op = reinterpret_cast<float4*>(C + (size_t)row * 256 + cb * BN + tx * 8);
            op[0] = make_float4(o[0], o[1], o[2], o[3]);
            op[1] = make_float4(o[4], o[5], o[6], o[7]);
        }
    }
}

// ---------------- skinny GEMM: Y[M,40] = A[M,256] @ W3[256,40] ----------------
__global__ __launch_bounds__(256) void k_gemm40(const float* __restrict__ A,
                                                const float* __restrict__ W,
                                                float* __restrict__ Y, int M) {
    __shared__ float Ws[256 * DOUT];
    const float4* Wv = reinterpret_cast<const float4*>(W);
    float4* Sv = reinterpret_cast<float4*>(Ws);
    for (int i = threadIdx.x; i < 256 * DOUT / 4; i += 256) Sv[i] = Wv[i];
    __syncthreads();
    int r = blockIdx.x * 64 + (threadIdx.x >> 2);
    int cg = (threadIdx.x & 3) * 10;
    if (r >= M) return;
    float acc[10];
    #pragma unroll
    for (int j = 0; j < 10; ++j) acc[j] = 0.f;
    const float* Ar = A + (size_t)r * 256;
    for (int k = 0; k < 256; ++k) {
        float a = Ar[k];
        #pragma unroll
        for (int j = 0; j < 10; ++j) acc[j] += a * Ws[k * DOUT + cg + j];
    }
    #pragma unroll
    for (int j = 0; j < 10; ++j) Y[(size_t)r * DOUT + cg + j] = acc[j];
}

// ---------------- SpMM D=40 fused with +b3 and log_softmax ----------------
__global__ __launch_bounds__(256) void k_spmm40_lsm(const float* __restrict__ y,
                                                    const int* __restrict__ offs,
                                                    const int* __restrict__ csr_src,
                                                    const float* __restrict__ csr_w,
                                                    const float* __restrict__ inv_in,
                                                    const float* __restrict__ b3,
                                                    float* __restrict__ out, int n) {
    int wid = (blockIdx.x * 256 + threadIdx.x) >> 6;
    int lane = threadIdx.x & 63;
    if (wid >= n) return;
    int beg = offs[wid], end = offs[wid + 1];
    bool act = lane < DOUT;
    float acc = 0.f;
    for (int j = beg; j < end; ++j) {
        int s = csr_src[j];
        float w = csr_w[j];
        if (act) acc += w * y[(size_t)s * DOUT + lane];
    }
    float v = act ? fmaf(inv_in[wid], acc, b3[lane]) : -INFINITY;
    float m = v;
    #pragma unroll
    for (int o = 32; o > 0; o >>= 1) m = fmaxf(m, __shfl_xor(m, o));
    float e = act ? __expf(v - m) : 0.f;
    float ssum = e;
    #pragma unroll
    for (int o = 32; o > 0; o >>= 1) ssum += __shfl_xor(ssum, o);
    float ls = logf(ssum);
    if (act) out[(size_t)wid * DOUT + lane] = v - m - ls;
}

extern "C" void kernel_launch(void* const* d_in, const int* in_sizes, int n_in,
                              void* d_out, int out_size, void* d_ws, size_t ws_size,
                              hipStream_t stream) {
    const float* x  = (const float*)d_in[0];
    const float* W1 = (const float*)d_in[1];
    const float* b1 = (const float*)d_in[2];
    const float* W2 = (const float*)d_in[3];
    const float* b2 = (const float*)d_in[4];
    const float* W3 = (const float*)d_in[5];
    const float* b3 = (const float*)d_in[6];
    const int* src  = (const int*)d_in[7];
    const int* dst  = (const int*)d_in[8];
    const int N = in_sizes[0] / D;   // 100000
    const int E = in_sizes[7];       // 1600000
    float* out = (float*)d_out;

    // workspace layout (~220 MB)
    char* p = (char*)d_ws;
    auto alloc = [&](size_t bytes) {
        char* r = p;
        p += (bytes + 255) & ~(size_t)255;
        return r;
    };
    int*   zeroz   = (int*)alloc((size_t)3 * N * sizeof(int));  // outdeg | indeg | cursor
    int*   offs    = (int*)alloc((size_t)(N + 1) * sizeof(int));
    int*   csr_src = (int*)alloc((size_t)E * sizeof(int));
    float* inv_out = (float*)alloc((size_t)N * sizeof(float));
    float* inv_in  = (float*)alloc((size_t)N * sizeof(float));
    float* csr_w   = (float*)alloc((size_t)E * sizeof(float));
    float* bufA    = (float*)alloc((size_t)N * D * sizeof(float));
    float* bufB    = (float*)alloc((size_t)N * D * sizeof(float));
    float* y40     = bufA;  // reuse: gemm40 reads bufB, writes bufA region
    int* outdeg = zeroz;
    int* indeg  = zeroz + N;
    int* cursor = zeroz + 2 * N;

    // graph preprocessing
    hipMemsetAsync(zeroz, 0, (size_t)3 * N * sizeof(int), stream);
    k_degree<<<(E + 255) / 256, 256, 0, stream>>>(src, dst, outdeg, indeg, E);
    k_invsqrt<<<(N + 255) / 256, 256, 0, stream>>>(outdeg, indeg, inv_out, inv_in, N);
    k_scan<<<1, 1024, 0, stream>>>(indeg, offs, N);
    k_scatter<<<(E + 255) / 256, 256, 0, stream>>>(src, dst, offs, cursor, inv_out,
                                                   csr_src, csr_w, E);

    dim3 gemmGrid((N + BM - 1) / BM, 256 / BN);
    // layer 1: agg = norm-SpMM(x); h1 = relu(agg @ W1 + b1)
    k_spmm256<<<(N + 3) / 4, 256, 0, stream>>>(x, offs, csr_src, csr_w, inv_in, bufA, N);
    k_gemm_fused<<<gemmGrid, 256, 0, stream>>>(bufA, W1, b1, bufB, N, 1);
    // layer 2
    k_spmm256<<<(N + 3) / 4, 256, 0, stream>>>(bufB, offs, csr_src, csr_w, inv_in, bufA, N);
    k_gemm_fused<<<gemmGrid, 256, 0, stream>>>(bufA, W2, b2, bufB, N, 1);
    // layer 3 (reassociated): y = h2 @ W3 ; out = lsm(norm-SpMM(y) + b3)
    k_gemm40<<<(N + 63) / 64, 256, 0, stream>>>(bufB, W3, y40, N);
    k_spmm40_lsm<<<(N + 3) / 4, 256, 0, stream>>>(y40, offs, csr_src, csr_w, inv_in,
                                                  b3, out, N);
}

// Round 3
// 1026.183 us; speedup vs baseline: 1.4688x; 1.4688x over previous
//
#include <hip/hip_runtime.h>
#include <hip/hip_bf16.h>
#include <math.h>

#define D 256
#define DOUT 40

typedef __attribute__((ext_vector_type(8))) short short8;
typedef __attribute__((ext_vector_type(4))) float f32x4;

__device__ __forceinline__ float lo_bf(unsigned w) {
    union { unsigned u; float f; } c; c.u = w << 16; return c.f;
}
__device__ __forceinline__ float hi_bf(unsigned w) {
    union { unsigned u; float f; } c; c.u = w & 0xffff0000u; return c.f;
}
__device__ __forceinline__ float b2f(unsigned short u) {
    union { unsigned u; float f; } c; c.u = ((unsigned)u) << 16; return c.f;
}
__device__ __forceinline__ unsigned short f2b(float f) {
    __hip_bfloat16 h = __float2bfloat16(f);   // RNE
    return reinterpret_cast<unsigned short&>(h);
}

// ---------------- degree histogram ----------------
__global__ __launch_bounds__(256) void k_degree(const int* __restrict__ src,
                                                const int* __restrict__ dst,
                                                int* __restrict__ outdeg,
                                                int* __restrict__ indeg, int E) {
    int e = blockIdx.x * 256 + threadIdx.x;
    if (e < E) {
        atomicAdd(&outdeg[src[e]], 1);
        atomicAdd(&indeg[dst[e]], 1);
    }
}

// ---------------- inv-sqrt norm factors ----------------
__global__ __launch_bounds__(256) void k_invsqrt(const int* __restrict__ outdeg,
                                                 const int* __restrict__ indeg,
                                                 float* __restrict__ inv_out,
                                                 float* __restrict__ inv_in, int n) {
    int i = blockIdx.x * 256 + threadIdx.x;
    if (i < n) {
        int od = outdeg[i], idg = indeg[i];
        inv_out[i] = od > 0 ? rsqrtf((float)od) : 0.0f;
        inv_in[i]  = idg > 0 ? rsqrtf((float)idg) : 0.0f;
    }
}

// ---------------- one-block exclusive scan (offsets) ----------------
__global__ __launch_bounds__(1024) void k_scan(const int* __restrict__ deg,
                                               int* __restrict__ offs, int n) {
    __shared__ int wsum[16];
    __shared__ int s_carry;
    int tid = threadIdx.x;
    int lane = tid & 63, wv = tid >> 6;
    if (tid == 0) s_carry = 0;
    __syncthreads();
    for (int base = 0; base < n; base += 1024) {
        int i = base + tid;
        int v = (i < n) ? deg[i] : 0;
        int x = v;
        #pragma unroll
        for (int o = 1; o < 64; o <<= 1) {
            int t = __shfl_up(x, o);
            if (lane >= o) x += t;
        }
        if (lane == 63) wsum[wv] = x;
        __syncthreads();
        if (wv == 0 && lane < 16) {
            int y = wsum[lane];
            #pragma unroll
            for (int o = 1; o < 16; o <<= 1) {
                int t = __shfl_up(y, o);
                if (lane >= o) y += t;
            }
            wsum[lane] = y;
        }
        __syncthreads();
        int waveoff = (wv == 0) ? 0 : wsum[wv - 1];
        if (i < n) offs[i] = s_carry + waveoff + x - v;
        __syncthreads();
        if (tid == 0) s_carry += wsum[15];
        __syncthreads();
    }
    if (threadIdx.x == 0) offs[n] = s_carry;
}

// ---------------- CSR scatter (group edges by dst) ----------------
__global__ __launch_bounds__(256) void k_scatter(const int* __restrict__ src,
                                                 const int* __restrict__ dst,
                                                 const int* __restrict__ offs,
                                                 int* __restrict__ cursor,
                                                 const float* __restrict__ inv_out,
                                                 int* __restrict__ csr_src,
                                                 float* __restrict__ csr_w, int E) {
    int e = blockIdx.x * 256 + threadIdx.x;
    if (e < E) {
        int d = dst[e], s = src[e];
        int p = atomicAdd(&cursor[d], 1);
        int idx = offs[d] + p;
        csr_src[idx] = s;
        csr_w[idx] = inv_out[s];
    }
}

// ---------------- f32 -> bf16 conversion (x) ----------------
__global__ __launch_bounds__(256) void k_cvt_x(const float* __restrict__ in,
                                               unsigned short* __restrict__ out,
                                               long long n8) {
    long long i = (long long)blockIdx.x * 256 + threadIdx.x;
    if (i >= n8) return;
    const float4* p = reinterpret_cast<const float4*>(in) + i * 2;
    float4 a = p[0], b = p[1];
    uint4 o;
    o.x = (unsigned)f2b(a.x) | ((unsigned)f2b(a.y) << 16);
    o.y = (unsigned)f2b(a.z) | ((unsigned)f2b(a.w) << 16);
    o.z = (unsigned)f2b(b.x) | ((unsigned)f2b(b.y) << 16);
    o.w = (unsigned)f2b(b.z) | ((unsigned)f2b(b.w) << 16);
    reinterpret_cast<uint4*>(out)[i] = o;
}

// ---------------- W[256,256] f32 -> Wt[n][k] bf16 ----------------
__global__ __launch_bounds__(256) void k_cvt_wt(const float* __restrict__ W,
                                                unsigned short* __restrict__ Wt) {
    int n = blockIdx.x, k = threadIdx.x;
    Wt[n * 256 + k] = f2b(W[k * 256 + n]);
}

// ---------------- W3[256,40] f32 -> Wt3[128 pad][256] bf16 ----------------
__global__ __launch_bounds__(256) void k_cvt_wt3(const float* __restrict__ W3,
                                                 unsigned short* __restrict__ Wt3) {
    int n = blockIdx.x, k = threadIdx.x;
    float v = (n < DOUT) ? W3[k * DOUT + n] : 0.0f;
    Wt3[n * 256 + k] = f2b(v);
}

// ---------------- SpMM bf16, D=256: one wave per dst node ----------------
__global__ __launch_bounds__(256) void k_spmm256b(const unsigned short* __restrict__ h,
                                                  const int* __restrict__ offs,
                                                  const int* __restrict__ csr_src,
                                                  const float* __restrict__ csr_w,
                                                  const float* __restrict__ inv_in,
                                                  unsigned short* __restrict__ out, int n) {
    int wid = (blockIdx.x * 256 + threadIdx.x) >> 6;
    int lane = threadIdx.x & 63;
    if (wid >= n) return;
    int beg = offs[wid], end = offs[wid + 1];
    float a0 = 0.f, a1 = 0.f, a2 = 0.f, a3 = 0.f;
    int j = beg;
    for (; j + 4 <= end; j += 4) {
        int s0 = csr_src[j], s1 = csr_src[j + 1], s2 = csr_src[j + 2], s3 = csr_src[j + 3];
        float w0 = csr_w[j], w1 = csr_w[j + 1], w2 = csr_w[j + 2], w3 = csr_w[j + 3];
        uint2 v0 = reinterpret_cast<const uint2*>(h + (size_t)s0 * D)[lane];
        uint2 v1 = reinterpret_cast<const uint2*>(h + (size_t)s1 * D)[lane];
        uint2 v2 = reinterpret_cast<const uint2*>(h + (size_t)s2 * D)[lane];
        uint2 v3 = reinterpret_cast<const uint2*>(h + (size_t)s3 * D)[lane];
        a0 += w0 * lo_bf(v0.x); a1 += w0 * hi_bf(v0.x); a2 += w0 * lo_bf(v0.y); a3 += w0 * hi_bf(v0.y);
        a0 += w1 * lo_bf(v1.x); a1 += w1 * hi_bf(v1.x); a2 += w1 * lo_bf(v1.y); a3 += w1 * hi_bf(v1.y);
        a0 += w2 * lo_bf(v2.x); a1 += w2 * hi_bf(v2.x); a2 += w2 * lo_bf(v2.y); a3 += w2 * hi_bf(v2.y);
        a0 += w3 * lo_bf(v3.x); a1 += w3 * hi_bf(v3.x); a2 += w3 * lo_bf(v3.y); a3 += w3 * hi_bf(v3.y);
    }
    for (; j < end; ++j) {
        int s = csr_src[j];
        float w = csr_w[j];
        uint2 v = reinterpret_cast<const uint2*>(h + (size_t)s * D)[lane];
        a0 += w * lo_bf(v.x); a1 += w * hi_bf(v.x); a2 += w * lo_bf(v.y); a3 += w * hi_bf(v.y);
    }
    float sc = inv_in[wid];
    uint2 r;
    r.x = (unsigned)f2b(sc * a0) | ((unsigned)f2b(sc * a1) << 16);
    r.y = (unsigned)f2b(sc * a2) | ((unsigned)f2b(sc * a3) << 16);
    reinterpret_cast<uint2*>(out + (size_t)wid * D)[lane] = r;
}

// ---------------- bf16 MFMA GEMM: C[M,ldc] = act(A[M,256] @ Wt^T + b) ----------------
// A: bf16 row-major [M][256]. Wt: bf16 [ncols_panelized][256] (row n = col n of W).
// flags: bit0 = relu, bit1 = add bias.
__global__ __launch_bounds__(256) void k_gemm_mfma(const unsigned short* __restrict__ A,
                                                   const unsigned short* __restrict__ Wt,
                                                   const float* __restrict__ bias,
                                                   unsigned short* __restrict__ C,
                                                   int M, int ldc, int ncols, int flags) {
    __shared__ unsigned short As[128][40];  // pad 40: b128 reads ~2-way (free)
    __shared__ unsigned short Bs[128][40];
    int tid = threadIdx.x;
    int lane = tid & 63, wave = tid >> 6;
    int wr = wave >> 1, wc = wave & 1;
    int rowBase = blockIdx.x * 128;
    int colBase = blockIdx.y * 128;

    f32x4 acc[4][4];
    #pragma unroll
    for (int m = 0; m < 4; ++m)
        #pragma unroll
        for (int n = 0; n < 4; ++n) acc[m][n] = (f32x4){0.f, 0.f, 0.f, 0.f};

    int ar = lane & 15, kg = lane >> 4;

    for (int k0 = 0; k0 < 256; k0 += 32) {
        // stage A panel: 128 rows x 32 k (chunks: row=c>>2, kc=c&3, 16B each)
        #pragma unroll
        for (int hh = 0; hh < 2; ++hh) {
            int c = tid + hh * 256;
            int row = c >> 2, kc = c & 3;
            int grow = rowBase + row;
            uint4 v = make_uint4(0, 0, 0, 0);
            if (grow < M)
                v = *reinterpret_cast<const uint4*>(A + (size_t)grow * 256 + k0 + kc * 8);
            *reinterpret_cast<uint4*>(&As[row][kc * 8]) = v;
        }
        // stage B panel (Wt rows are weight columns; layer-3 Wt is zero-padded to 128)
        #pragma unroll
        for (int hh = 0; hh < 2; ++hh) {
            int c = tid + hh * 256;
            int col = c >> 2, kc = c & 3;
            int gcol = colBase + col;
            uint4 v = *reinterpret_cast<const uint4*>(Wt + (size_t)gcol * 256 + k0 + kc * 8);
            *reinterpret_cast<uint4*>(&Bs[col][kc * 8]) = v;
        }
        __syncthreads();
        short8 a[4], b[4];
        #pragma unroll
        for (int m = 0; m < 4; ++m)
            a[m] = *reinterpret_cast<const short8*>(&As[wr * 64 + m * 16 + ar][kg * 8]);
        #pragma unroll
        for (int n = 0; n < 4; ++n)
            b[n] = *reinterpret_cast<const short8*>(&Bs[wc * 64 + n * 16 + ar][kg * 8]);
        #pragma unroll
        for (int m = 0; m < 4; ++m)
            #pragma unroll
            for (int n = 0; n < 4; ++n)
                acc[m][n] = __builtin_amdgcn_mfma_f32_16x16x32_bf16(a[m], b[n], acc[m][n], 0, 0, 0);
        __syncthreads();
    }

    // epilogue: C/D layout col=lane&15, row=(lane>>4)*4+r
    int rq = lane >> 4, cl = lane & 15;
    float bv[4];
    #pragma unroll
    for (int n = 0; n < 4; ++n) {
        int col = colBase + wc * 64 + n * 16 + cl;
        bv[n] = ((flags & 2) && col < ncols) ? bias[col] : 0.f;
    }
    #pragma unroll
    for (int m = 0; m < 4; ++m) {
        #pragma unroll
        for (int n = 0; n < 4; ++n) {
            int col = colBase + wc * 64 + n * 16 + cl;
            if (col >= ncols) continue;
            #pragma unroll
            for (int r = 0; r < 4; ++r) {
                int row = rowBase + wr * 64 + m * 16 + rq * 4 + r;
                if (row < M) {
                    float v = acc[m][n][r] + bv[n];
                    if (flags & 1) v = fmaxf(v, 0.f);
                    C[(size_t)row * ldc + col] = f2b(v);
                }
            }
        }
    }
}

// ---------------- SpMM D=40 (bf16 in) fused with +b3 and log_softmax ----------------
__global__ __launch_bounds__(256) void k_spmm40_lsm(const unsigned short* __restrict__ y,
                                                    const int* __restrict__ offs,
                                                    const int* __restrict__ csr_src,
                                                    const float* __restrict__ csr_w,
                                                    const float* __restrict__ inv_in,
                                                    const float* __restrict__ b3,
                                                    float* __restrict__ out, int n) {
    int wid = (blockIdx.x * 256 + threadIdx.x) >> 6;
    int lane = threadIdx.x & 63;
    if (wid >= n) return;
    int beg = offs[wid], end = offs[wid + 1];
    bool act = lane < DOUT;
    float acc = 0.f;
    for (int j = beg; j < end; ++j) {
        int s = csr_src[j];
        float w = csr_w[j];
        if (act) acc += w * b2f(y[(size_t)s * DOUT + lane]);
    }
    float v = act ? fmaf(inv_in[wid], acc, b3[lane]) : -INFINITY;
    float m = v;
    #pragma unroll
    for (int o = 32; o > 0; o >>= 1) m = fmaxf(m, __shfl_xor(m, o));
    float e = act ? __expf(v - m) : 0.f;
    float ssum = e;
    #pragma unroll
    for (int o = 32; o > 0; o >>= 1) ssum += __shfl_xor(ssum, o);
    float ls = logf(ssum);
    if (act) out[(size_t)wid * DOUT + lane] = v - m - ls;
}

extern "C" void kernel_launch(void* const* d_in, const int* in_sizes, int n_in,
                              void* d_out, int out_size, void* d_ws, size_t ws_size,
                              hipStream_t stream) {
    const float* x  = (const float*)d_in[0];
    const float* W1 = (const float*)d_in[1];
    const float* b1 = (const float*)d_in[2];
    const float* W2 = (const float*)d_in[3];
    const float* b2 = (const float*)d_in[4];
    const float* W3 = (const float*)d_in[5];
    const float* b3 = (const float*)d_in[6];
    const int* src  = (const int*)d_in[7];
    const int* dst  = (const int*)d_in[8];
    const int N = in_sizes[0] / D;   // 100000
    const int E = in_sizes[7];       // 1600000
    float* out = (float*)d_out;

    // workspace layout (~170 MB)
    char* p = (char*)d_ws;
    auto alloc = [&](size_t bytes) {
        char* r = p;
        p += (bytes + 255) & ~(size_t)255;
        return r;
    };
    int*   zeroz   = (int*)alloc((size_t)3 * N * sizeof(int));  // outdeg | indeg | cursor
    int*   offs    = (int*)alloc((size_t)(N + 1) * sizeof(int));
    int*   csr_src = (int*)alloc((size_t)E * sizeof(int));
    float* inv_out = (float*)alloc((size_t)N * sizeof(float));
    float* inv_in  = (float*)alloc((size_t)N * sizeof(float));
    float* csr_w   = (float*)alloc((size_t)E * sizeof(float));
    unsigned short* Wt1 = (unsigned short*)alloc((size_t)256 * 256 * 2);
    unsigned short* Wt2 = (unsigned short*)alloc((size_t)256 * 256 * 2);
    unsigned short* Wt3 = (unsigned short*)alloc((size_t)128 * 256 * 2);
    unsigned short* buf0 = (unsigned short*)alloc((size_t)N * D * 2);  // xb -> g2 -> z40
    unsigned short* buf1 = (unsigned short*)alloc((size_t)N * D * 2);  // g1 -> h2
    unsigned short* buf2 = (unsigned short*)alloc((size_t)N * D * 2);  // h1
    int* outdeg = zeroz;
    int* indeg  = zeroz + N;
    int* cursor = zeroz + 2 * N;

    // graph preprocessing
    hipMemsetAsync(zeroz, 0, (size_t)3 * N * sizeof(int), stream);
    k_degree<<<(E + 255) / 256, 256, 0, stream>>>(src, dst, outdeg, indeg, E);
    k_invsqrt<<<(N + 255) / 256, 256, 0, stream>>>(outdeg, indeg, inv_out, inv_in, N);
    k_scan<<<1, 1024, 0, stream>>>(indeg, offs, N);
    k_scatter<<<(E + 255) / 256, 256, 0, stream>>>(src, dst, offs, cursor, inv_out,
                                                   csr_src, csr_w, E);

    // weight conversion (tiny)
    k_cvt_wt<<<256, 256, 0, stream>>>(W1, Wt1);
    k_cvt_wt<<<256, 256, 0, stream>>>(W2, Wt2);
    k_cvt_wt3<<<128, 256, 0, stream>>>(W3, Wt3);

    // x -> bf16
    long long n8 = (long long)N * D / 8;
    k_cvt_x<<<(int)((n8 + 255) / 256), 256, 0, stream>>>(x, buf0, n8);

    dim3 gemmGrid((N + 127) / 128, 2);
    dim3 gemmGrid40((N + 127) / 128, 1);
    // layer 1
    k_spmm256b<<<(N + 3) / 4, 256, 0, stream>>>(buf0, offs, csr_src, csr_w, inv_in, buf1, N);
    k_gemm_mfma<<<gemmGrid, 256, 0, stream>>>(buf1, Wt1, b1, buf2, N, 256, 256, 3);
    // layer 2
    k_spmm256b<<<(N + 3) / 4, 256, 0, stream>>>(buf2, offs, csr_src, csr_w, inv_in, buf0, N);
    k_gemm_mfma<<<gemmGrid, 256, 0, stream>>>(buf0, Wt2, b2, buf1, N, 256, 256, 3);
    // layer 3 (reassociated): z = h2 @ W3 (no bias, no relu); out = lsm(norm-SpMM(z) + b3)
    k_gemm_mfma<<<gemmGrid40, 256, 0, stream>>>(buf1, Wt3, b3, buf0, N, DOUT, DOUT, 0);
    k_spmm40_lsm<<<(N + 3) / 4, 256, 0, stream>>>(buf0, offs, csr_src, csr_w, inv_in,
                                                  b3, out, N);
}

// Round 4
// 813.319 us; speedup vs baseline: 1.8532x; 1.2617x over previous
//
#include <hip/hip_runtime.h>
#include <hip/hip_bf16.h>
#include <math.h>

#define D 256
#define DOUT 40

typedef __attribute__((ext_vector_type(8))) short short8;
typedef __attribute__((ext_vector_type(4))) float f32x4;

__device__ __forceinline__ float lo_bf(unsigned w) {
    union { unsigned u; float f; } c; c.u = w << 16; return c.f;
}
__device__ __forceinline__ float hi_bf(unsigned w) {
    union { unsigned u; float f; } c; c.u = w & 0xffff0000u; return c.f;
}
__device__ __forceinline__ float b2f(unsigned short u) {
    union { unsigned u; float f; } c; c.u = ((unsigned)u) << 16; return c.f;
}
__device__ __forceinline__ unsigned short f2b(float f) {
    __hip_bfloat16 h = __float2bfloat16(f);   // RNE
    return reinterpret_cast<unsigned short&>(h);
}

// ---------------- degree histogram ----------------
__global__ __launch_bounds__(256) void k_degree(const int* __restrict__ src,
                                                const int* __restrict__ dst,
                                                int* __restrict__ outdeg,
                                                int* __restrict__ indeg, int E) {
    int e = blockIdx.x * 256 + threadIdx.x;
    if (e < E) {
        atomicAdd(&outdeg[src[e]], 1);
        atomicAdd(&indeg[dst[e]], 1);
    }
}

// ---------------- inv-sqrt norm factors ----------------
__global__ __launch_bounds__(256) void k_invsqrt(const int* __restrict__ outdeg,
                                                 const int* __restrict__ indeg,
                                                 float* __restrict__ inv_out,
                                                 float* __restrict__ inv_in, int n) {
    int i = blockIdx.x * 256 + threadIdx.x;
    if (i < n) {
        int od = outdeg[i], idg = indeg[i];
        inv_out[i] = od > 0 ? rsqrtf((float)od) : 0.0f;
        inv_in[i]  = idg > 0 ? rsqrtf((float)idg) : 0.0f;
    }
}

// ---------------- hierarchical exclusive scan ----------------
// phase 1: per-block (1024) exclusive scan + block sums
__global__ __launch_bounds__(1024) void k_scan1(const int* __restrict__ deg,
                                                int* __restrict__ offs,
                                                int* __restrict__ bsum, int n) {
    __shared__ int wsum[16];
    int tid = threadIdx.x, lane = tid & 63, wv = tid >> 6;
    int i = blockIdx.x * 1024 + tid;
    int v = (i < n) ? deg[i] : 0;
    int x = v;
    #pragma unroll
    for (int o = 1; o < 64; o <<= 1) {
        int t = __shfl_up(x, o);
        if (lane >= o) x += t;
    }
    if (lane == 63) wsum[wv] = x;
    __syncthreads();
    if (wv == 0 && lane < 16) {
        int y = wsum[lane];
        #pragma unroll
        for (int o = 1; o < 16; o <<= 1) {
            int t = __shfl_up(y, o);
            if (lane >= o) y += t;
        }
        wsum[lane] = y;
    }
    __syncthreads();
    int waveoff = wv ? wsum[wv - 1] : 0;
    if (i < n) offs[i] = waveoff + x - v;
    if (tid == 0) bsum[blockIdx.x] = wsum[15];
}

// phase 2: single-wave exclusive scan of block sums (loops with carry)
__global__ __launch_bounds__(64) void k_scan2(int* __restrict__ bsum, int G) {
    int lane = threadIdx.x;
    int carry = 0;
    for (int base = 0; base < G; base += 64) {
        int idx = base + lane;
        int v = (idx < G) ? bsum[idx] : 0;
        int x = v;
        #pragma unroll
        for (int o = 1; o < 64; o <<= 1) {
            int t = __shfl_up(x, o);
            if (lane >= o) x += t;
        }
        int tot = __shfl(x, 63);
        if (idx < G) bsum[idx] = carry + x - v;
        carry += tot;
    }
}

// phase 3: add block offsets; offs[n] = E (sum of indeg is exactly E)
__global__ __launch_bounds__(1024) void k_scan3(int* __restrict__ offs,
                                                const int* __restrict__ bsum,
                                                int n, int E) {
    int i = blockIdx.x * 1024 + threadIdx.x;
    if (i < n) offs[i] += bsum[blockIdx.x];
    if (i == 0) offs[n] = E;
}

// ---------------- CSR scatter (group edges by dst) ----------------
__global__ __launch_bounds__(256) void k_scatter(const int* __restrict__ src,
                                                 const int* __restrict__ dst,
                                                 const int* __restrict__ offs,
                                                 int* __restrict__ cursor,
                                                 const float* __restrict__ inv_out,
                                                 int* __restrict__ csr_src,
                                                 float* __restrict__ csr_w, int E) {
    int e = blockIdx.x * 256 + threadIdx.x;
    if (e < E) {
        int d = dst[e], s = src[e];
        int p = atomicAdd(&cursor[d], 1);
        int idx = offs[d] + p;
        csr_src[idx] = s;
        csr_w[idx] = inv_out[s];
    }
}

// ---------------- f32 -> bf16 conversion (x) ----------------
__global__ __launch_bounds__(256) void k_cvt_x(const float* __restrict__ in,
                                               unsigned short* __restrict__ out,
                                               long long n8) {
    long long i = (long long)blockIdx.x * 256 + threadIdx.x;
    if (i >= n8) return;
    const float4* p = reinterpret_cast<const float4*>(in) + i * 2;
    float4 a = p[0], b = p[1];
    uint4 o;
    o.x = (unsigned)f2b(a.x) | ((unsigned)f2b(a.y) << 16);
    o.y = (unsigned)f2b(a.z) | ((unsigned)f2b(a.w) << 16);
    o.z = (unsigned)f2b(b.x) | ((unsigned)f2b(b.y) << 16);
    o.w = (unsigned)f2b(b.z) | ((unsigned)f2b(b.w) << 16);
    reinterpret_cast<uint4*>(out)[i] = o;
}

// ---------------- W[256,256] f32 -> Wt[n][k] bf16 ----------------
__global__ __launch_bounds__(256) void k_cvt_wt(const float* __restrict__ W,
                                                unsigned short* __restrict__ Wt) {
    int n = blockIdx.x, k = threadIdx.x;
    Wt[n * 256 + k] = f2b(W[k * 256 + n]);
}

// ---------------- W3[256,40] f32 -> Wt3[64 pad][256] bf16 ----------------
__global__ __launch_bounds__(256) void k_cvt_wt3(const float* __restrict__ W3,
                                                 unsigned short* __restrict__ Wt3) {
    int n = blockIdx.x, k = threadIdx.x;
    float v = (n < DOUT) ? W3[k * DOUT + n] : 0.0f;
    Wt3[n * 256 + k] = f2b(v);
}

// ---------------- SpMM bf16, D=256: one wave per dst node ----------------
__global__ __launch_bounds__(256) void k_spmm256b(const unsigned short* __restrict__ h,
                                                  const int* __restrict__ offs,
                                                  const int* __restrict__ csr_src,
                                                  const float* __restrict__ csr_w,
                                                  const float* __restrict__ inv_in,
                                                  unsigned short* __restrict__ out, int n) {
    int wid = (blockIdx.x * 256 + threadIdx.x) >> 6;
    int lane = threadIdx.x & 63;
    if (wid >= n) return;
    int beg = offs[wid], end = offs[wid + 1];
    float a0 = 0.f, a1 = 0.f, a2 = 0.f, a3 = 0.f;
    int j = beg;
    for (; j + 4 <= end; j += 4) {
        int s0 = csr_src[j], s1 = csr_src[j + 1], s2 = csr_src[j + 2], s3 = csr_src[j + 3];
        float w0 = csr_w[j], w1 = csr_w[j + 1], w2 = csr_w[j + 2], w3 = csr_w[j + 3];
        uint2 v0 = reinterpret_cast<const uint2*>(h + (size_t)s0 * D)[lane];
        uint2 v1 = reinterpret_cast<const uint2*>(h + (size_t)s1 * D)[lane];
        uint2 v2 = reinterpret_cast<const uint2*>(h + (size_t)s2 * D)[lane];
        uint2 v3 = reinterpret_cast<const uint2*>(h + (size_t)s3 * D)[lane];
        a0 += w0 * lo_bf(v0.x); a1 += w0 * hi_bf(v0.x); a2 += w0 * lo_bf(v0.y); a3 += w0 * hi_bf(v0.y);
        a0 += w1 * lo_bf(v1.x); a1 += w1 * hi_bf(v1.x); a2 += w1 * lo_bf(v1.y); a3 += w1 * hi_bf(v1.y);
        a0 += w2 * lo_bf(v2.x); a1 += w2 * hi_bf(v2.x); a2 += w2 * lo_bf(v2.y); a3 += w2 * hi_bf(v2.y);
        a0 += w3 * lo_bf(v3.x); a1 += w3 * hi_bf(v3.x); a2 += w3 * lo_bf(v3.y); a3 += w3 * hi_bf(v3.y);
    }
    for (; j < end; ++j) {
        int s = csr_src[j];
        float w = csr_w[j];
        uint2 v = reinterpret_cast<const uint2*>(h + (size_t)s * D)[lane];
        a0 += w * lo_bf(v.x); a1 += w * hi_bf(v.x); a2 += w * lo_bf(v.y); a3 += w * hi_bf(v.y);
    }
    float sc = inv_in[wid];
    uint2 r;
    r.x = (unsigned)f2b(sc * a0) | ((unsigned)f2b(sc * a1) << 16);
    r.y = (unsigned)f2b(sc * a2) | ((unsigned)f2b(sc * a3) << 16);
    reinterpret_cast<uint2*>(out + (size_t)wid * D)[lane] = r;
}

// ---------------- bf16 MFMA GEMM: C[M,ldc] = act(A[M,256] @ Wt^T + b) ----------------
// A: bf16 row-major [M][256]. Wt: bf16 [ncols_panelized][256] (row n = col n of W).
// flags: bit0 = relu, bit1 = add bias.
__global__ __launch_bounds__(256) void k_gemm_mfma(const unsigned short* __restrict__ A,
                                                   const unsigned short* __restrict__ Wt,
                                                   const float* __restrict__ bias,
                                                   unsigned short* __restrict__ C,
                                                   int M, int ldc, int ncols, int flags) {
    __shared__ unsigned short As[128][40];  // pad 40: b128 reads ~2-way (free)
    __shared__ unsigned short Bs[128][40];
    int tid = threadIdx.x;
    int lane = tid & 63, wave = tid >> 6;
    int wr = wave >> 1, wc = wave & 1;
    int rowBase = blockIdx.x * 128;
    int colBase = blockIdx.y * 128;

    f32x4 acc[4][4];
    #pragma unroll
    for (int m = 0; m < 4; ++m)
        #pragma unroll
        for (int n = 0; n < 4; ++n) acc[m][n] = (f32x4){0.f, 0.f, 0.f, 0.f};

    int ar = lane & 15, kg = lane >> 4;

    for (int k0 = 0; k0 < 256; k0 += 32) {
        #pragma unroll
        for (int hh = 0; hh < 2; ++hh) {
            int c = tid + hh * 256;
            int row = c >> 2, kc = c & 3;
            int grow = rowBase + row;
            uint4 v = make_uint4(0, 0, 0, 0);
            if (grow < M)
                v = *reinterpret_cast<const uint4*>(A + (size_t)grow * 256 + k0 + kc * 8);
            *reinterpret_cast<uint4*>(&As[row][kc * 8]) = v;
        }
        #pragma unroll
        for (int hh = 0; hh < 2; ++hh) {
            int c = tid + hh * 256;
            int col = c >> 2, kc = c & 3;
            int gcol = colBase + col;
            uint4 v = *reinterpret_cast<const uint4*>(Wt + (size_t)gcol * 256 + k0 + kc * 8);
            *reinterpret_cast<uint4*>(&Bs[col][kc * 8]) = v;
        }
        __syncthreads();
        short8 a[4], b[4];
        #pragma unroll
        for (int m = 0; m < 4; ++m)
            a[m] = *reinterpret_cast<const short8*>(&As[wr * 64 + m * 16 + ar][kg * 8]);
        #pragma unroll
        for (int n = 0; n < 4; ++n)
            b[n] = *reinterpret_cast<const short8*>(&Bs[wc * 64 + n * 16 + ar][kg * 8]);
        #pragma unroll
        for (int m = 0; m < 4; ++m)
            #pragma unroll
            for (int n = 0; n < 4; ++n)
                acc[m][n] = __builtin_amdgcn_mfma_f32_16x16x32_bf16(a[m], b[n], acc[m][n], 0, 0, 0);
        __syncthreads();
    }

    // epilogue: C/D layout col=lane&15, row=(lane>>4)*4+r
    int rq = lane >> 4, cl = lane & 15;
    float bv[4];
    #pragma unroll
    for (int n = 0; n < 4; ++n) {
        int col = colBase + wc * 64 + n * 16 + cl;
        bv[n] = ((flags & 2) && col < ncols) ? bias[col] : 0.f;
    }
    #pragma unroll
    for (int m = 0; m < 4; ++m) {
        #pragma unroll
        for (int n = 0; n < 4; ++n) {
            int col = colBase + wc * 64 + n * 16 + cl;
            if (col >= ncols) continue;
            #pragma unroll
            for (int r = 0; r < 4; ++r) {
                int row = rowBase + wr * 64 + m * 16 + rq * 4 + r;
                if (row < M) {
                    float v = acc[m][n][r] + bv[n];
                    if (flags & 1) v = fmaxf(v, 0.f);
                    C[(size_t)row * ldc + col] = f2b(v);
                }
            }
        }
    }
}

// ---------------- bf16 MFMA GEMM, 128x64 tile (skinny N, e.g. W3) ----------------
// 4 waves stacked in rows: wave w covers rows w*32..w*32+31, all 64 cols.
__global__ __launch_bounds__(256) void k_gemm_mfma64(const unsigned short* __restrict__ A,
                                                     const unsigned short* __restrict__ Wt,
                                                     unsigned short* __restrict__ C,
                                                     int M, int ldc, int ncols) {
    __shared__ unsigned short As[128][40];
    __shared__ unsigned short Bs[64][40];
    int tid = threadIdx.x;
    int lane = tid & 63, wave = tid >> 6;
    int rowBase = blockIdx.x * 128;

    f32x4 acc[2][4];
    #pragma unroll
    for (int m = 0; m < 2; ++m)
        #pragma unroll
        for (int n = 0; n < 4; ++n) acc[m][n] = (f32x4){0.f, 0.f, 0.f, 0.f};

    int ar = lane & 15, kg = lane >> 4;

    for (int k0 = 0; k0 < 256; k0 += 32) {
        #pragma unroll
        for (int hh = 0; hh < 2; ++hh) {
            int c = tid + hh * 256;
            int row = c >> 2, kc = c & 3;
            int grow = rowBase + row;
            uint4 v = make_uint4(0, 0, 0, 0);
            if (grow < M)
                v = *reinterpret_cast<const uint4*>(A + (size_t)grow * 256 + k0 + kc * 8);
            *reinterpret_cast<uint4*>(&As[row][kc * 8]) = v;
        }
        {
            int col = tid >> 2, kc = tid & 3;
            uint4 v = *reinterpret_cast<const uint4*>(Wt + (size_t)col * 256 + k0 + kc * 8);
            *reinterpret_cast<uint4*>(&Bs[col][kc * 8]) = v;
        }
        __syncthreads();
        short8 a[2], b[4];
        #pragma unroll
        for (int m = 0; m < 2; ++m)
            a[m] = *reinterpret_cast<const short8*>(&As[wave * 32 + m * 16 + ar][kg * 8]);
        #pragma unroll
        for (int n = 0; n < 4; ++n)
            b[n] = *reinterpret_cast<const short8*>(&Bs[n * 16 + ar][kg * 8]);
        #pragma unroll
        for (int m = 0; m < 2; ++m)
            #pragma unroll
            for (int n = 0; n < 4; ++n)
                acc[m][n] = __builtin_amdgcn_mfma_f32_16x16x32_bf16(a[m], b[n], acc[m][n], 0, 0, 0);
        __syncthreads();
    }

    int rq = lane >> 4, cl = lane & 15;
    #pragma unroll
    for (int m = 0; m < 2; ++m) {
        #pragma unroll
        for (int n = 0; n < 4; ++n) {
            int col = n * 16 + cl;
            if (col >= ncols) continue;
            #pragma unroll
            for (int r = 0; r < 4; ++r) {
                int row = rowBase + wave * 32 + m * 16 + rq * 4 + r;
                if (row < M) C[(size_t)row * ldc + col] = f2b(acc[m][n][r]);
            }
        }
    }
}

// ---------------- SpMM D=40 (bf16 in) fused with +b3 and log_softmax ----------------
// All 64 lanes load unconditionally (reads past col 39 stay inside the
// over-allocated buffer); only lanes <40 contribute to the result.
__global__ __launch_bounds__(256) void k_spmm40_lsm(const unsigned short* __restrict__ y,
                                                    const int* __restrict__ offs,
                                                    const int* __restrict__ csr_src,
                                                    const float* __restrict__ csr_w,
                                                    const float* __restrict__ inv_in,
                                                    const float* __restrict__ b3,
                                                    float* __restrict__ out, int n) {
    int wid = (blockIdx.x * 256 + threadIdx.x) >> 6;
    int lane = threadIdx.x & 63;
    if (wid >= n) return;
    int beg = offs[wid], end = offs[wid + 1];
    float acc = 0.f;
    int j = beg;
    for (; j + 4 <= end; j += 4) {
        int s0 = csr_src[j], s1 = csr_src[j + 1], s2 = csr_src[j + 2], s3 = csr_src[j + 3];
        float w0 = csr_w[j], w1 = csr_w[j + 1], w2 = csr_w[j + 2], w3 = csr_w[j + 3];
        float v0 = b2f(y[(size_t)s0 * DOUT + lane]);
        float v1 = b2f(y[(size_t)s1 * DOUT + lane]);
        float v2 = b2f(y[(size_t)s2 * DOUT + lane]);
        float v3 = b2f(y[(size_t)s3 * DOUT + lane]);
        acc += w0 * v0 + w1 * v1 + w2 * v2 + w3 * v3;
    }
    for (; j < end; ++j) {
        int s = csr_src[j];
        acc += csr_w[j] * b2f(y[(size_t)s * DOUT + lane]);
    }
    bool act = lane < DOUT;
    float v = act ? fmaf(inv_in[wid], acc, b3[lane]) : -INFINITY;
    float m = v;
    #pragma unroll
    for (int o = 32; o > 0; o >>= 1) m = fmaxf(m, __shfl_xor(m, o));
    float e = act ? __expf(v - m) : 0.f;
    float ssum = e;
    #pragma unroll
    for (int o = 32; o > 0; o >>= 1) ssum += __shfl_xor(ssum, o);
    float ls = logf(ssum);
    if (act) out[(size_t)wid * DOUT + lane] = v - m - ls;
}

extern "C" void kernel_launch(void* const* d_in, const int* in_sizes, int n_in,
                              void* d_out, int out_size, void* d_ws, size_t ws_size,
                              hipStream_t stream) {
    const float* x  = (const float*)d_in[0];
    const float* W1 = (const float*)d_in[1];
    const float* b1 = (const float*)d_in[2];
    const float* W2 = (const float*)d_in[3];
    const float* b2 = (const float*)d_in[4];
    const float* W3 = (const float*)d_in[5];
    const float* b3 = (const float*)d_in[6];
    const int* src  = (const int*)d_in[7];
    const int* dst  = (const int*)d_in[8];
    const int N = in_sizes[0] / D;   // 100000
    const int E = in_sizes[7];       // 1600000
    float* out = (float*)d_out;

    // workspace layout (~170 MB)
    char* p = (char*)d_ws;
    auto alloc = [&](size_t bytes) {
        char* r = p;
        p += (bytes + 255) & ~(size_t)255;
        return r;
    };
    int*   zeroz   = (int*)alloc((size_t)3 * N * sizeof(int));  // outdeg | indeg | cursor
    int*   offs    = (int*)alloc((size_t)(N + 1) * sizeof(int));
    int*   bsum    = (int*)alloc((size_t)1024 * sizeof(int));
    int*   csr_src = (int*)alloc((size_t)E * sizeof(int));
    float* inv_out = (float*)alloc((size_t)N * sizeof(float));
    float* inv_in  = (float*)alloc((size_t)N * sizeof(float));
    float* csr_w   = (float*)alloc((size_t)E * sizeof(float));
    unsigned short* Wt1 = (unsigned short*)alloc((size_t)256 * 256 * 2);
    unsigned short* Wt2 = (unsigned short*)alloc((size_t)256 * 256 * 2);
    unsigned short* Wt3 = (unsigned short*)alloc((size_t)64 * 256 * 2);
    unsigned short* buf0 = (unsigned short*)alloc((size_t)N * D * 2);  // xb -> g2 -> z40
    unsigned short* buf1 = (unsigned short*)alloc((size_t)N * D * 2);  // g1 -> h2
    unsigned short* buf2 = (unsigned short*)alloc((size_t)N * D * 2);  // h1
    int* outdeg = zeroz;
    int* indeg  = zeroz + N;
    int* cursor = zeroz + 2 * N;

    // graph preprocessing
    hipMemsetAsync(zeroz, 0, (size_t)3 * N * sizeof(int), stream);
    k_degree<<<(E + 255) / 256, 256, 0, stream>>>(src, dst, outdeg, indeg, E);
    k_invsqrt<<<(N + 255) / 256, 256, 0, stream>>>(outdeg, indeg, inv_out, inv_in, N);
    int G = (N + 1023) / 1024;
    k_scan1<<<G, 1024, 0, stream>>>(indeg, offs, bsum, N);
    k_scan2<<<1, 64, 0, stream>>>(bsum, G);
    k_scan3<<<G, 1024, 0, stream>>>(offs, bsum, N, E);
    k_scatter<<<(E + 255) / 256, 256, 0, stream>>>(src, dst, offs, cursor, inv_out,
                                                   csr_src, csr_w, E);

    // weight conversion (tiny)
    k_cvt_wt<<<256, 256, 0, stream>>>(W1, Wt1);
    k_cvt_wt<<<256, 256, 0, stream>>>(W2, Wt2);
    k_cvt_wt3<<<64, 256, 0, stream>>>(W3, Wt3);

    // x -> bf16
    long long n8 = (long long)N * D / 8;
    k_cvt_x<<<(int)((n8 + 255) / 256), 256, 0, stream>>>(x, buf0, n8);

    dim3 gemmGrid((N + 127) / 128, 2);
    // layer 1
    k_spmm256b<<<(N + 3) / 4, 256, 0, stream>>>(buf0, offs, csr_src, csr_w, inv_in, buf1, N);
    k_gemm_mfma<<<gemmGrid, 256, 0, stream>>>(buf1, Wt1, b1, buf2, N, 256, 256, 3);
    // layer 2
    k_spmm256b<<<(N + 3) / 4, 256, 0, stream>>>(buf2, offs, csr_src, csr_w, inv_in, buf0, N);
    k_gemm_mfma<<<gemmGrid, 256, 0, stream>>>(buf0, Wt2, b2, buf1, N, 256, 256, 3);
    // layer 3 (reassociated): z = h2 @ W3 (no bias/relu); out = lsm(norm-SpMM(z) + b3)
    k_gemm_mfma64<<<(N + 127) / 128, 256, 0, stream>>>(buf1, Wt3, buf0, N, DOUT, DOUT);
    k_spmm40_lsm<<<(N + 3) / 4, 256, 0, stream>>>(buf0, offs, csr_src, csr_w, inv_in,
                                                  b3, out, N);
}